// Round 2
// baseline (688.827 us; speedup 1.0000x reference)
//
#include <hip/hip_runtime.h>
#include <math.h>

#define LRELU_SLOPE 0.2f

__device__ __forceinline__ float lrelu(float x){ return x >= 0.f ? x : LRELU_SLOPE*x; }
__device__ __forceinline__ float eluf(float x){ return x > 0.f ? x : expm1f(x); }

// ---------------------------------------------------------------------------
// CSR build (by dst). Edge list = edge_index columns + n self loops.
// ---------------------------------------------------------------------------
__global__ void k_hist(const int* __restrict__ ei, int E, int n, int* __restrict__ cnt){
    int e = blockIdx.x*blockDim.x + threadIdx.x;
    int NE = E + n;
    if (e >= NE) return;
    int d = (e < E) ? ei[E + e] : (e - E);
    atomicAdd(&cnt[d], 1);
}

__global__ __launch_bounds__(1024) void k_scan(const int* __restrict__ cnt, int n,
                                               int* __restrict__ off, int* __restrict__ cur){
    __shared__ int part[1024];
    const int ITEMS = (n + 1023) / 1024;
    int t = threadIdx.x;
    int base = t * ITEMS;
    int s = 0;
    for (int i = 0; i < ITEMS; i++){ int idx = base + i; if (idx < n) s += cnt[idx]; }
    part[t] = s;
    __syncthreads();
    for (int d = 1; d < 1024; d <<= 1){
        int v = 0;
        if (t >= d) v = part[t - d];
        __syncthreads();
        if (t >= d) part[t] += v;
        __syncthreads();
    }
    int excl = part[t] - s;   // exclusive prefix of this thread's chunk
    for (int i = 0; i < ITEMS; i++){
        int idx = base + i;
        if (idx < n){ off[idx] = excl; cur[idx] = excl; excl += cnt[idx]; }
    }
    if (t == 1023) off[n] = part[1023];
}

__global__ void k_scatter(const int* __restrict__ ei, int E, int n,
                          int* __restrict__ cur, int* __restrict__ esrc){
    int e = blockIdx.x*blockDim.x + threadIdx.x;
    int NE = E + n;
    if (e >= NE) return;
    int s = (e < E) ? ei[e]     : (e - E);
    int d = (e < E) ? ei[E + e] : (e - E);
    int pos = atomicAdd(&cur[d], 1);
    esrc[pos] = s;
}

// ---------------------------------------------------------------------------
// fp32 GEMM: C[M,N] = A[M,K] @ B[N,K]^T (+bias). 64x64 tile, 256 threads,
// 4x4 microtile. K multiple of 32, N multiple of 64; M ragged (guarded).
// ---------------------------------------------------------------------------
__global__ __launch_bounds__(256) void k_gemm_nt(
    const float* __restrict__ A, const float* __restrict__ B,
    const float* __restrict__ bias, float* __restrict__ C,
    int M, int N, int K)
{
    const int BM = 64, BN = 64, BK = 32, PAD = 4;
    __shared__ float As[BK][BM + PAD];
    __shared__ float Bs[BK][BN + PAD];
    int tid = threadIdx.x;
    int tx = tid & 15;          // m direction (16)
    int ty = tid >> 4;          // n direction (16)
    int m0 = blockIdx.x * BM;
    int n0 = blockIdx.y * BN;
    float acc[4][4] = {};

    int lm = tid >> 3;          // 0..31
    int lk = (tid & 7) * 4;     // 0,4,...,28

    for (int k0 = 0; k0 < K; k0 += BK){
        #pragma unroll
        for (int r = 0; r < 2; r++){
            int m = lm + 32*r;
            int row = m0 + m;
            float4 v = make_float4(0.f,0.f,0.f,0.f);
            if (row < M) v = *(const float4*)&A[(size_t)row*K + k0 + lk];
            As[lk+0][m] = v.x; As[lk+1][m] = v.y; As[lk+2][m] = v.z; As[lk+3][m] = v.w;
        }
        #pragma unroll
        for (int r = 0; r < 2; r++){
            int nn = lm + 32*r;
            int col = n0 + nn;
            float4 v = make_float4(0.f,0.f,0.f,0.f);
            if (col < N) v = *(const float4*)&B[(size_t)col*K + k0 + lk];
            Bs[lk+0][nn] = v.x; Bs[lk+1][nn] = v.y; Bs[lk+2][nn] = v.z; Bs[lk+3][nn] = v.w;
        }
        __syncthreads();
        #pragma unroll
        for (int kk = 0; kk < BK; kk++){
            float4 a = *(const float4*)&As[kk][tx*4];
            float4 b = *(const float4*)&Bs[kk][ty*4];
            float av[4] = {a.x,a.y,a.z,a.w};
            float bv[4] = {b.x,b.y,b.z,b.w};
            #pragma unroll
            for (int i = 0; i < 4; i++)
                #pragma unroll
                for (int j = 0; j < 4; j++)
                    acc[i][j] = fmaf(av[i], bv[j], acc[i][j]);
        }
        __syncthreads();
    }

    float4 bb = make_float4(0.f,0.f,0.f,0.f);
    if (bias) bb = *(const float4*)&bias[n0 + ty*4];
    #pragma unroll
    for (int i = 0; i < 4; i++){
        int row = m0 + tx*4 + i;
        if (row >= M) continue;
        float4 v = make_float4(acc[i][0]+bb.x, acc[i][1]+bb.y, acc[i][2]+bb.z, acc[i][3]+bb.w);
        *(float4*)&C[(size_t)row*N + n0 + ty*4] = v;
    }
}

// ---------------------------------------------------------------------------
// Per-node attention scalars: a_s[i,h] = h[i,h,:]·att_s[h,:], same for a_d.
// One wave (64 lanes) per node; C=128.
// ---------------------------------------------------------------------------
template<int H>
__global__ __launch_bounds__(64) void k_att(
    const float* __restrict__ h, const float* __restrict__ att_s,
    const float* __restrict__ att_d, int n,
    float* __restrict__ as_, float* __restrict__ ad_)
{
    const int C = 128;
    int i = blockIdx.x;
    int l = threadIdx.x;
    const float* hrow = h + (size_t)i * H * C;
    #pragma unroll
    for (int hh = 0; hh < H; hh++){
        float h0v = hrow[hh*C + l], h1v = hrow[hh*C + l + 64];
        float ps = h0v*att_s[hh*C + l] + h1v*att_s[hh*C + l + 64];
        float pd = h0v*att_d[hh*C + l] + h1v*att_d[hh*C + l + 64];
        #pragma unroll
        for (int o = 32; o > 0; o >>= 1){ ps += __shfl_down(ps, o); pd += __shfl_down(pd, o); }
        if (l == 0){ as_[(size_t)i*H + hh] = ps; ad_[(size_t)i*H + hh] = pd; }
    }
}

// ---------------------------------------------------------------------------
// GAT softmax + aggregation, one block per dst node. C=128, F=H*128.
// out[d,:] = elu( (sum_e exp(alpha_e)-weighted h[src_e,:]) / (denom+1e-16) + bias )
// ---------------------------------------------------------------------------
template<int H, int NT>
__global__ __launch_bounds__(NT) void k_agg(
    const float* __restrict__ hfeat,   // n x F
    const float* __restrict__ as_,     // n x H
    const float* __restrict__ ad_,     // n x H
    const int* __restrict__ off, const int* __restrict__ esrc,
    const float* __restrict__ bias,    // F
    float* __restrict__ out, int n)
{
    const int C = 128, F = H * C;
    const int PC = F / NT;             // channels per thread (2 or 1)
    const int NW = NT / 64;
    int d = blockIdx.x;
    int t = threadIdx.x;
    int lane = t & 63, wv = t >> 6;
    int e0 = off[d], e1 = off[d+1];

    __shared__ float red[NW][H];
    __shared__ float m_sh[H], iden_sh[H];
    __shared__ int   src_l[64];
    __shared__ float exw[64][H];

    float adl[H];
    #pragma unroll
    for (int hh = 0; hh < H; hh++) adl[hh] = ad_[(size_t)d*H + hh];

    // Phase A: segment max per head
    float mloc[H];
    #pragma unroll
    for (int hh = 0; hh < H; hh++) mloc[hh] = -1e30f;
    for (int e = e0 + t; e < e1; e += NT){
        int s = esrc[e];
        #pragma unroll
        for (int hh = 0; hh < H; hh++)
            mloc[hh] = fmaxf(mloc[hh], lrelu(as_[(size_t)s*H + hh] + adl[hh]));
    }
    #pragma unroll
    for (int hh = 0; hh < H; hh++){
        float v = mloc[hh];
        #pragma unroll
        for (int o = 32; o > 0; o >>= 1) v = fmaxf(v, __shfl_down(v, o));
        if (lane == 0) red[wv][hh] = v;
    }
    __syncthreads();
    if (t == 0){
        #pragma unroll
        for (int hh = 0; hh < H; hh++){
            float v = red[0][hh];
            for (int w = 1; w < NW; w++) v = fmaxf(v, red[w][hh]);
            m_sh[hh] = v;
        }
    }
    __syncthreads();
    float m[H];
    #pragma unroll
    for (int hh = 0; hh < H; hh++) m[hh] = m_sh[hh];

    // Phase B: denominator
    float dloc[H];
    #pragma unroll
    for (int hh = 0; hh < H; hh++) dloc[hh] = 0.f;
    for (int e = e0 + t; e < e1; e += NT){
        int s = esrc[e];
        #pragma unroll
        for (int hh = 0; hh < H; hh++)
            dloc[hh] += expf(lrelu(as_[(size_t)s*H + hh] + adl[hh]) - m[hh]);
    }
    __syncthreads();
    #pragma unroll
    for (int hh = 0; hh < H; hh++){
        float v = dloc[hh];
        #pragma unroll
        for (int o = 32; o > 0; o >>= 1) v += __shfl_down(v, o);
        if (lane == 0) red[wv][hh] = v;
    }
    __syncthreads();
    if (t == 0){
        #pragma unroll
        for (int hh = 0; hh < H; hh++){
            float v = red[0][hh];
            for (int w = 1; w < NW; w++) v += red[w][hh];
            iden_sh[hh] = 1.f / (v + 1e-16f);
        }
    }
    __syncthreads();

    // Phase C: feature accumulation in chunks of 64 edges
    float acc[PC];
    #pragma unroll
    for (int p = 0; p < PC; p++) acc[p] = 0.f;
    for (int cb = e0; cb < e1; cb += 64){
        int ce = min(64, e1 - cb);
        if (t < 64 * H){
            int eidx = t / H, hh = t % H;
            if (eidx < ce){
                int s = esrc[cb + eidx];
                if (hh == 0) src_l[eidx] = s;
                exw[eidx][hh] = expf(lrelu(as_[(size_t)s*H + hh] + adl[hh]) - m[hh]);
            }
        }
        __syncthreads();
        for (int e = 0; e < ce; e++){
            int s = src_l[e];
            const float* hr = hfeat + (size_t)s * F;
            #pragma unroll
            for (int p = 0; p < PC; p++){
                int c = t + p * NT;
                acc[p] = fmaf(exw[e][c >> 7], hr[c], acc[p]);
            }
        }
        __syncthreads();
    }

    #pragma unroll
    for (int p = 0; p < PC; p++){
        int c = t + p * NT;
        float v = acc[p] * iden_sh[c >> 7] + bias[c];
        out[(size_t)d * F + c] = eluf(v);
    }
}

// ---------------------------------------------------------------------------
// Edge scores: s1[i] = h3[i,:]·w1 + bedge, s2[i] = h3[i,:]·w2. One wave/node.
// ---------------------------------------------------------------------------
__global__ __launch_bounds__(64) void k_score(
    const float* __restrict__ h3, const float* __restrict__ wedge,
    const float* __restrict__ bedge, int n,
    float* __restrict__ s1, float* __restrict__ s2)
{
    int i = blockIdx.x, l = threadIdx.x;
    const float* hr = h3 + (size_t)i * 128;
    float h0v = hr[l], h1v = hr[l + 64];
    float p1 = h0v*wedge[l]       + h1v*wedge[l + 64];
    float p2 = h0v*wedge[128 + l] + h1v*wedge[192 + l];
    #pragma unroll
    for (int o = 32; o > 0; o >>= 1){ p1 += __shfl_down(p1, o); p2 += __shfl_down(p2, o); }
    if (l == 0){ s1[i] = p1 + bedge[0]; s2[i] = p2; }
}

// ---------------------------------------------------------------------------
// out[i,j] = s1[i] + s2[j]. One block per row, float4 stores.
// ---------------------------------------------------------------------------
__global__ __launch_bounds__(256) void k_outer(
    const float* __restrict__ s1, const float* __restrict__ s2,
    float* __restrict__ out, int n)
{
    int i = blockIdx.x;
    float a = s1[i];
    float4* orow = (float4*)(out + (size_t)i * n);
    const float4* s2v = (const float4*)s2;
    int nq = n >> 2;
    for (int j = threadIdx.x; j < nq; j += blockDim.x){
        float4 b = s2v[j];
        orow[j] = make_float4(a + b.x, a + b.y, a + b.z, a + b.w);
    }
    // ragged tail (n % 4) — not hit for n=10000 but kept for safety
    int rem0 = nq << 2;
    for (int j = rem0 + threadIdx.x; j < n; j += blockDim.x)
        out[(size_t)i * n + j] = a + s2[j];
}

// ---------------------------------------------------------------------------
extern "C" void kernel_launch(void* const* d_in, const int* in_sizes, int n_in,
                              void* d_out, int out_size, void* d_ws, size_t ws_size,
                              hipStream_t stream) {
    const float* x     = (const float*)d_in[0];
    const int*   ei    = (const int*)  d_in[1];
    const float* W0    = (const float*)d_in[2];
    const float* as0w  = (const float*)d_in[3];
    const float* ad0w  = (const float*)d_in[4];
    const float* b0    = (const float*)d_in[5];
    const float* W1    = (const float*)d_in[6];
    const float* as1w  = (const float*)d_in[7];
    const float* ad1w  = (const float*)d_in[8];
    const float* b1    = (const float*)d_in[9];
    const float* Wout  = (const float*)d_in[10];
    const float* boutp = (const float*)d_in[11];
    const float* Wedge = (const float*)d_in[12];
    const float* bedge = (const float*)d_in[13];

    const int hid    = in_sizes[7];                 // 128
    const int heads  = in_sizes[3] / hid;           // 4
    const int in_dim = in_sizes[2] / (heads * hid); // 128
    const int n      = in_sizes[0] / in_dim;        // 10000
    const int E      = in_sizes[1] / 2;             // 320000
    const int NE     = E + n;
    const int F0     = heads * hid;                 // 512

    // ---- workspace carving ----
    char* ws = (char*)d_ws;
    size_t pos = 0;
    auto alloc = [&](size_t bytes) -> void* {
        pos = (pos + 255) & ~size_t(255);
        void* p = ws + pos;
        pos += bytes;
        return p;
    };
    float* a0s = (float*)alloc((size_t)n * heads * 4);
    float* a0d = (float*)alloc((size_t)n * heads * 4);
    float* a1s = (float*)alloc((size_t)n * 4);
    float* a1d = (float*)alloc((size_t)n * 4);
    float* s1  = (float*)alloc((size_t)n * 4);
    float* s2  = (float*)alloc((size_t)n * 4);
    int*   cnt = (int*)  alloc((size_t)n * 4);
    int*   offs= (int*)  alloc((size_t)(n + 1) * 4);
    int*   cur = (int*)  alloc((size_t)n * 4);

    // big buffers: in ws if they fit, else carve from d_out (dead before k_outer)
    auto al = [](size_t b){ return (b + 255) & ~size_t(255); };
    size_t b_esrc = al((size_t)NE * 4);
    size_t b_h0   = al((size_t)n * F0 * 4);
    size_t b_o1   = al((size_t)n * F0 * 4);
    size_t b_h1   = al((size_t)n * hid * 4);
    size_t b_o2   = al((size_t)n * hid * 4);
    size_t b_h3   = al((size_t)n * hid * 4);
    size_t big_need = b_esrc + b_h0 + b_o1 + b_h1 + b_o2 + b_h3;
    size_t small_end = (pos + 255) & ~size_t(255);
    char* big = (small_end + big_need <= ws_size) ? (ws + small_end) : (char*)d_out;
    size_t bp = 0;
    int*   esrc = (int*)  (big + bp); bp += b_esrc;
    float* h0   = (float*)(big + bp); bp += b_h0;
    float* o1   = (float*)(big + bp); bp += b_o1;
    float* h1   = (float*)(big + bp); bp += b_h1;
    float* o2   = (float*)(big + bp); bp += b_o2;
    float* h3   = (float*)(big + bp); bp += b_h3;

    // ---- CSR build (shared by both GAT layers) ----
    (void)hipMemsetAsync(cnt, 0, (size_t)n * 4, stream);
    int tb = 256, gbE = (NE + tb - 1) / tb;
    k_hist   <<<gbE, tb, 0, stream>>>(ei, E, n, cnt);
    k_scan   <<<1, 1024, 0, stream>>>(cnt, n, offs, cur);
    k_scatter<<<gbE, tb, 0, stream>>>(ei, E, n, cur, esrc);

    int gx = (n + 63) / 64;

    // ---- Layer 1: h0 = x @ W0^T ; attention scalars ; aggregate -> o1 ----
    k_gemm_nt<<<dim3(gx, F0/64), 256, 0, stream>>>(x, W0, nullptr, h0, n, F0, in_dim);
    k_att<4> <<<n, 64, 0, stream>>>(h0, as0w, ad0w, n, a0s, a0d);
    k_agg<4, 256><<<n, 256, 0, stream>>>(h0, a0s, a0d, offs, esrc, b0, o1, n);

    // ---- Layer 2: h1 = o1 @ W1^T ; aggregate -> o2 ----
    k_gemm_nt<<<dim3(gx, hid/64), 256, 0, stream>>>(o1, W1, nullptr, h1, n, hid, F0);
    k_att<1> <<<n, 64, 0, stream>>>(h1, as1w, ad1w, n, a1s, a1d);
    k_agg<1, 128><<<n, 128, 0, stream>>>(h1, a1s, a1d, offs, esrc, b1, o2, n);

    // ---- h3 = o2 @ Wout^T + bout ----
    k_gemm_nt<<<dim3(gx, hid/64), 256, 0, stream>>>(o2, Wout, boutp, h3, n, hid, hid);

    // ---- edge scores + outer sum ----
    k_score<<<n, 64, 0, stream>>>(h3, Wedge, bedge, n, s1, s2);
    k_outer<<<n, 256, 0, stream>>>(s1, s2, (float*)d_out, n);
}